// Round 7
// baseline (439.280 us; speedup 1.0000x reference)
//
#include <hip/hip_runtime.h>
#include <math.h>

#define NN 50000
#define NE 800000
#define NEG 0.2f
#define NB 196  // ceil(NN/256)

// ---------- fused dual GEMM: out[N,256] = feat[N,128] @ W + b  (gridDim.y picks W1s/W1d)
__global__ __launch_bounds__(256) void gemm_proj(
    const float* __restrict__ feat,
    const float* __restrict__ Wa, const float* __restrict__ ba, float* __restrict__ outa,
    const float* __restrict__ Wb, const float* __restrict__ bb, float* __restrict__ outb,
    int n_rows)
{
    const float* W = blockIdx.y ? Wb : Wa;
    const float* bv = blockIdx.y ? bb : ba;
    float* out = blockIdx.y ? outb : outa;

    __shared__ float fT[64][128];
    __shared__ float wT[16][256];

    const int row0 = blockIdx.x * 64;
    const int tid = threadIdx.x;

    {
        const float4* f4 = reinterpret_cast<const float4*>(feat);
#pragma unroll
        for (int p = 0; p < 8; ++p) {
            int idx = p * 256 + tid;
            int r = idx >> 5, c4 = idx & 31;
            int gr = row0 + r;
            float4 v = (gr < n_rows) ? f4[(size_t)gr * 32 + c4]
                                     : make_float4(0.f, 0.f, 0.f, 0.f);
            *reinterpret_cast<float4*>(&fT[r][c4 * 4]) = v;
        }
    }

    const int tm = tid >> 5;
    const int tn = tid & 31;
    float acc[8][8];
#pragma unroll
    for (int ri = 0; ri < 8; ++ri)
#pragma unroll
        for (int ci = 0; ci < 8; ++ci) acc[ri][ci] = 0.0f;

    const float4* W4 = reinterpret_cast<const float4*>(W);
    for (int k0 = 0; k0 < 128; k0 += 16) {
        __syncthreads();
#pragma unroll
        for (int p = 0; p < 4; ++p) {
            int idx = p * 256 + tid;
            int r = idx >> 6, c4 = idx & 63;
            *reinterpret_cast<float4*>(&wT[r][c4 * 4]) = W4[(size_t)(k0 + r) * 64 + c4];
        }
        __syncthreads();
#pragma unroll
        for (int kk = 0; kk < 16; ++kk) {
            float a[8], w[8];
#pragma unroll
            for (int ri = 0; ri < 8; ++ri) a[ri] = fT[tm + ri * 8][k0 + kk];
#pragma unroll
            for (int ci = 0; ci < 8; ++ci) w[ci] = wT[kk][tn + ci * 32];
#pragma unroll
            for (int ri = 0; ri < 8; ++ri)
#pragma unroll
                for (int ci = 0; ci < 8; ++ci)
                    acc[ri][ci] = fmaf(a[ri], w[ci], acc[ri][ci]);
        }
    }
#pragma unroll
    for (int ri = 0; ri < 8; ++ri) {
        int row = row0 + tm + ri * 8;
        if (row < n_rows) {
#pragma unroll
            for (int ci = 0; ci < 8; ++ci) {
                int col = tn + ci * 32;
                out[(size_t)row * 256 + col] = acc[ri][ci] + bv[col];
            }
        }
    }
}

// ---------------- CSR build ----------------
__global__ void count_deg(const int* __restrict__ dst, int* __restrict__ deg)
{
    int e = blockIdx.x * blockDim.x + threadIdx.x;
    if (e < NE) atomicAdd(&deg[dst[e]], 1);
}

__global__ __launch_bounds__(256) void deg_blocksum(const int* __restrict__ deg,
                                                    int* __restrict__ bsum)
{
    int i = blockIdx.x * 256 + threadIdx.x;
    int v = (i < NN) ? deg[i] : 0;
#pragma unroll
    for (int off = 32; off; off >>= 1) v += __shfl_xor(v, off);
    __shared__ int ws[4];
    if ((threadIdx.x & 63) == 0) ws[threadIdx.x >> 6] = v;
    __syncthreads();
    if (threadIdx.x == 0) bsum[blockIdx.x] = ws[0] + ws[1] + ws[2] + ws[3];
}

__global__ __launch_bounds__(256) void scan_bsum(int* __restrict__ bsum)
{
    __shared__ int tmp[256];
    int t = threadIdx.x;
    int orig = (t < NB) ? bsum[t] : 0;
    tmp[t] = orig;
    __syncthreads();
    for (int off = 1; off < 256; off <<= 1) {
        int v = (t >= off) ? tmp[t - off] : 0;
        __syncthreads();
        tmp[t] += v;
        __syncthreads();
    }
    if (t < NB) bsum[t] = tmp[t] - orig;  // exclusive prefix
}

__global__ __launch_bounds__(256) void write_rows(const int* __restrict__ deg,
                                                  const int* __restrict__ bpre,
                                                  int* __restrict__ row_start)
{
    int i = blockIdx.x * 256 + threadIdx.x;
    int d = (i < NN) ? deg[i] : 0;
    int lane = threadIdx.x & 63, w = threadIdx.x >> 6;
    int x = d;
#pragma unroll
    for (int off = 1; off < 64; off <<= 1) {
        int v = __shfl_up(x, off);
        if (lane >= off) x += v;
    }
    __shared__ int wsum[4];
    if (lane == 63) wsum[w] = x;
    __syncthreads();
    int woff = 0;
#pragma unroll
    for (int k = 0; k < 4; ++k)
        if (k < w) woff += wsum[k];
    if (i < NN) row_start[i] = bpre[blockIdx.x] + woff + x - d;
    if (blockIdx.x == 0 && threadIdx.x == 0) row_start[NN] = NE;
}

// cursor pre-initialized to row_start values (D2D copy) -> absolute positions
__global__ void scatter_src(const int* __restrict__ src, const int* __restrict__ dst,
                            int* __restrict__ cursor, int* __restrict__ src_sorted)
{
    int e = blockIdx.x * blockDim.x + threadIdx.x;
    if (e < NE) {
        int pos = atomicAdd(&cursor[dst[e]], 1);
        src_sorted[pos] = src[e];
    }
}

// ---- Layer-1 fused, single pass, 16 lanes per edge (4 edges per wave per iter).
//      lane q of a group owns dims [hh*64 + (q&3)*16, +16) where hh=q>>2.
__global__ __launch_bounds__(256) void gat1_fused(
    const float* __restrict__ hs, const float* __restrict__ hd,
    const float* __restrict__ attn, const int* __restrict__ src_sorted,
    const int* __restrict__ row_start,
    const float* __restrict__ W2s, const float* __restrict__ b2s,
    const float* __restrict__ W2d, const float* __restrict__ b2d,
    float* __restrict__ hs2, float* __restrict__ hd2)
{
    __shared__ float acc_lds[4][16][20];  // [wave][q][dim16], pad 20 (16B-aligned, 2-way)
    __shared__ float m_lds[4][4], d_lds[4][4];

    const int n = blockIdx.x;
    const int tid = threadIdx.x;
    const int w = tid >> 6;
    const int lane = tid & 63;
    const int g = lane >> 4;          // edge slot within wave
    const int q = lane & 15;          // lane within edge group
    const int hh = q >> 2;            // head owned by this lane
    const int dim0 = hh * 64 + (q & 3) * 16;
    const int beg = row_start[n], end_ = row_start[n + 1];

    const float4 a0 = *reinterpret_cast<const float4*>(&attn[dim0 + 0]);
    const float4 a1 = *reinterpret_cast<const float4*>(&attn[dim0 + 4]);
    const float4 a2 = *reinterpret_cast<const float4*>(&attn[dim0 + 8]);
    const float4 a3 = *reinterpret_cast<const float4*>(&attn[dim0 + 12]);
    const float4 y0 = *reinterpret_cast<const float4*>(&hd[(size_t)n * 256 + dim0 + 0]);
    const float4 y1 = *reinterpret_cast<const float4*>(&hd[(size_t)n * 256 + dim0 + 4]);
    const float4 y2 = *reinterpret_cast<const float4*>(&hd[(size_t)n * 256 + dim0 + 8]);
    const float4 y3 = *reinterpret_cast<const float4*>(&hd[(size_t)n * 256 + dim0 + 12]);

    float m = -INFINITY, den = 0.0f;
    float4 c0 = make_float4(0.f, 0.f, 0.f, 0.f), c1 = c0, c2 = c0, c3 = c0;

    for (int i = beg + (w << 2) + g; i < end_; i += 16) {
        const int s = src_sorted[i];  // same addr across 16-lane group
        const float4* xp = reinterpret_cast<const float4*>(&hs[(size_t)s * 256 + dim0]);
        const float4 x0 = xp[0], x1 = xp[1], x2 = xp[2], x3 = xp[3];
        float t, p;
        t = x0.x + y0.x; t = fmaxf(t, NEG * t); p  = t * a0.x;
        t = x0.y + y0.y; t = fmaxf(t, NEG * t); p = fmaf(t, a0.y, p);
        t = x0.z + y0.z; t = fmaxf(t, NEG * t); p = fmaf(t, a0.z, p);
        t = x0.w + y0.w; t = fmaxf(t, NEG * t); p = fmaf(t, a0.w, p);
        t = x1.x + y1.x; t = fmaxf(t, NEG * t); p = fmaf(t, a1.x, p);
        t = x1.y + y1.y; t = fmaxf(t, NEG * t); p = fmaf(t, a1.y, p);
        t = x1.z + y1.z; t = fmaxf(t, NEG * t); p = fmaf(t, a1.z, p);
        t = x1.w + y1.w; t = fmaxf(t, NEG * t); p = fmaf(t, a1.w, p);
        t = x2.x + y2.x; t = fmaxf(t, NEG * t); p = fmaf(t, a2.x, p);
        t = x2.y + y2.y; t = fmaxf(t, NEG * t); p = fmaf(t, a2.y, p);
        t = x2.z + y2.z; t = fmaxf(t, NEG * t); p = fmaf(t, a2.z, p);
        t = x2.w + y2.w; t = fmaxf(t, NEG * t); p = fmaf(t, a2.w, p);
        t = x3.x + y3.x; t = fmaxf(t, NEG * t); p = fmaf(t, a3.x, p);
        t = x3.y + y3.y; t = fmaxf(t, NEG * t); p = fmaf(t, a3.y, p);
        t = x3.z + y3.z; t = fmaxf(t, NEG * t); p = fmaf(t, a3.z, p);
        t = x3.w + y3.w; t = fmaxf(t, NEG * t); p = fmaf(t, a3.w, p);
        p += __shfl_xor(p, 1);
        p += __shfl_xor(p, 2);        // full head score, uniform across the quad
        if (p > m + 8.0f) {           // rare deferred rescale (T13)
            const float rs = __expf(m - p);  // first edge: exp(-inf)=0
            den *= rs;
            c0.x *= rs; c0.y *= rs; c0.z *= rs; c0.w *= rs;
            c1.x *= rs; c1.y *= rs; c1.z *= rs; c1.w *= rs;
            c2.x *= rs; c2.y *= rs; c2.z *= rs; c2.w *= rs;
            c3.x *= rs; c3.y *= rs; c3.z *= rs; c3.w *= rs;
            m = p;
        }
        const float wv = __expf(p - m);  // <= e^8; exact after final normalize
        den += wv;
        c0.x = fmaf(wv, x0.x, c0.x); c0.y = fmaf(wv, x0.y, c0.y);
        c0.z = fmaf(wv, x0.z, c0.z); c0.w = fmaf(wv, x0.w, c0.w);
        c1.x = fmaf(wv, x1.x, c1.x); c1.y = fmaf(wv, x1.y, c1.y);
        c1.z = fmaf(wv, x1.z, c1.z); c1.w = fmaf(wv, x1.w, c1.w);
        c2.x = fmaf(wv, x2.x, c2.x); c2.y = fmaf(wv, x2.y, c2.y);
        c2.z = fmaf(wv, x2.z, c2.z); c2.w = fmaf(wv, x2.w, c2.w);
        c3.x = fmaf(wv, x3.x, c3.x); c3.y = fmaf(wv, x3.y, c3.y);
        c3.z = fmaf(wv, x3.z, c3.z); c3.w = fmaf(wv, x3.w, c3.w);
    }

    // intra-wave online merge across the 4 edge slots (xor 16, then 32)
#pragma unroll
    for (int msk = 16; msk <= 32; msk <<= 1) {
        const float mo = __shfl_xor(m, msk);
        const float do_ = __shfl_xor(den, msk);
        const float M = fmaxf(m, mo);
        const float s1 = (m  > -INFINITY) ? __expf(m - M) : 0.0f;
        const float s2 = (mo > -INFINITY) ? __expf(mo - M) : 0.0f;
        den = den * s1 + do_ * s2;
#define MRG(cc) cc = cc * s1 + __shfl_xor(cc, msk) * s2;
        MRG(c0.x) MRG(c0.y) MRG(c0.z) MRG(c0.w)
        MRG(c1.x) MRG(c1.y) MRG(c1.z) MRG(c1.w)
        MRG(c2.x) MRG(c2.y) MRG(c2.z) MRG(c2.w)
        MRG(c3.x) MRG(c3.y) MRG(c3.z) MRG(c3.w)
#undef MRG
        m = M;
    }

    if (g == 0) {
        *reinterpret_cast<float4*>(&acc_lds[w][q][0])  = c0;
        *reinterpret_cast<float4*>(&acc_lds[w][q][4])  = c1;
        *reinterpret_cast<float4*>(&acc_lds[w][q][8])  = c2;
        *reinterpret_cast<float4*>(&acc_lds[w][q][12]) = c3;
        if ((q & 3) == 0) { m_lds[w][hh] = m; d_lds[w][hh] = den; }
    }
    __syncthreads();

    if (tid < 16) {  // wave 0, one lane per (head, dim-block)
        const int qq = tid;
        const int h2 = qq >> 2;
        const int db0 = h2 * 64 + (qq & 3) * 16;
        const float mA = m_lds[0][h2], mB = m_lds[1][h2];
        const float mC = m_lds[2][h2], mD = m_lds[3][h2];
        const float M = fmaxf(fmaxf(mA, mB), fmaxf(mC, mD));
        float o[16];
#pragma unroll
        for (int j = 0; j < 16; ++j) o[j] = 0.0f;
        float dtot = 0.0f;
#pragma unroll
        for (int k = 0; k < 4; ++k) {
            const float mk = m_lds[k][h2];
            const float sc = (mk > -INFINITY) ? __expf(mk - M) : 0.0f;
            dtot = fmaf(d_lds[k][h2], sc, dtot);
#pragma unroll
            for (int j = 0; j < 16; ++j) o[j] = fmaf(acc_lds[k][qq][j], sc, o[j]);
        }
        const float inv = (dtot > 0.0f) ? 1.0f / dtot : 0.0f;
        float ps0 = 0.f, ps1 = 0.f, pd0 = 0.f, pd1 = 0.f;
#pragma unroll
        for (int j = 0; j < 16; ++j) {
            float oj = o[j] * inv;
            oj = (oj > 0.0f) ? oj : __expf(oj) - 1.0f;  // ELU
            ps0 = fmaf(oj, W2s[(db0 + j) * 2 + 0], ps0);
            ps1 = fmaf(oj, W2s[(db0 + j) * 2 + 1], ps1);
            pd0 = fmaf(oj, W2d[(db0 + j) * 2 + 0], pd0);
            pd1 = fmaf(oj, W2d[(db0 + j) * 2 + 1], pd1);
        }
#pragma unroll
        for (int off = 1; off < 16; off <<= 1) {
            ps0 += __shfl_xor(ps0, off);
            ps1 += __shfl_xor(ps1, off);
            pd0 += __shfl_xor(pd0, off);
            pd1 += __shfl_xor(pd1, off);
        }
        if (qq == 0) {
            hs2[(size_t)n * 2 + 0] = ps0 + b2s[0];
            hs2[(size_t)n * 2 + 1] = ps1 + b2s[1];
            hd2[(size_t)n * 2 + 0] = pd0 + b2d[0];
            hd2[(size_t)n * 2 + 1] = pd1 + b2d[1];
        }
    }
}

// ---------------- Layer-2: wave per node, lane per edge ----------------
__global__ __launch_bounds__(256) void node2_kernel(
    const float* __restrict__ hs2, const float* __restrict__ hd2,
    const float* __restrict__ attn2, const int* __restrict__ src_sorted,
    const int* __restrict__ row_start, float* __restrict__ out)
{
    const int n = blockIdx.x * 4 + (threadIdx.x >> 6);
    const int lane = threadIdx.x & 63;
    if (n >= NN) return;
    const float a0 = attn2[0], a1 = attn2[1];
    const float h0 = hd2[n * 2 + 0], h1v = hd2[n * 2 + 1];
    const int beg = row_start[n], end_ = row_start[n + 1];
    float m = -INFINITY, den = 0.0f, A0 = 0.0f, A1 = 0.0f;
    for (int i = beg + lane; i < end_; i += 64) {
        const int s = src_sorted[i];
        float x0 = hs2[s * 2 + 0], x1 = hs2[s * 2 + 1];
        float t0 = x0 + h0;  t0 = fmaxf(t0, NEG * t0);
        float t1 = x1 + h1v; t1 = fmaxf(t1, NEG * t1);
        float p = fmaf(t0, a0, t1 * a1);
        float mn = fmaxf(m, p);
        float c = __expf(m - mn);
        float w = __expf(p - mn);
        den = den * c + w;
        A0 = A0 * c + w * x0;
        A1 = A1 * c + w * x1;
        m = mn;
    }
#pragma unroll
    for (int off = 1; off < 64; off <<= 1) {
        float m2 = __shfl_xor(m, off);
        float d2 = __shfl_xor(den, off);
        float b0 = __shfl_xor(A0, off);
        float b1 = __shfl_xor(A1, off);
        float mn = fmaxf(m, m2);
        float c1 = (m < mn) ? __expf(m - mn) : 1.0f;
        float c2 = (m2 < mn) ? __expf(m2 - mn) : 1.0f;
        den = den * c1 + d2 * c2;
        A0 = A0 * c1 + b0 * c2;
        A1 = A1 * c1 + b1 * c2;
        m = mn;
    }
    if (lane == 0) {
        out[n * 2 + 0] = (den > 0.0f) ? A0 / den : 0.0f;
        out[n * 2 + 1] = (den > 0.0f) ? A1 / den : 0.0f;
    }
}

// ---------------- launch ----------------
extern "C" void kernel_launch(void* const* d_in, const int* in_sizes, int n_in,
                              void* d_out, int out_size, void* d_ws, size_t ws_size,
                              hipStream_t stream)
{
    const float* feat  = (const float*)d_in[0];
    const int*   src   = (const int*)d_in[1];
    const int*   dst   = (const int*)d_in[2];
    const float* W1s   = (const float*)d_in[3];
    const float* b1s   = (const float*)d_in[4];
    const float* W1d   = (const float*)d_in[5];
    const float* b1d   = (const float*)d_in[6];
    const float* attn1 = (const float*)d_in[7];
    const float* W2s   = (const float*)d_in[8];
    const float* b2s   = (const float*)d_in[9];
    const float* W2d   = (const float*)d_in[10];
    const float* b2d   = (const float*)d_in[11];
    const float* attn2 = (const float*)d_in[12];
    float* out = (float*)d_out;

    char* ws = (char*)d_ws;
    size_t off = 0;
    auto alloc = [&](size_t bytes) {
        char* p = ws + off;
        off += (bytes + 255) & ~size_t(255);
        return p;
    };
    float* hs1        = (float*)alloc((size_t)NN * 256 * 4);
    float* hd1        = (float*)alloc((size_t)NN * 256 * 4);
    int*   src_sorted = (int*)alloc((size_t)NE * 4);
    int*   row_start  = (int*)alloc((size_t)(NN + 1) * 4);
    int*   deg        = (int*)alloc((size_t)NN * 4);
    int*   cursor     = (int*)alloc((size_t)NN * 4);
    int*   bsum       = (int*)alloc((size_t)NB * 4);
    float* hs2        = (float*)alloc((size_t)NN * 2 * 4);
    float* hd2        = (float*)alloc((size_t)NN * 2 * 4);
    (void)ws_size; (void)n_in; (void)in_sizes; (void)out_size;

    hipMemsetAsync(deg, 0, (size_t)NN * 4, stream);

    dim3 ggrid((NN + 63) / 64, 2);
    gemm_proj<<<ggrid, 256, 0, stream>>>(feat, W1s, b1s, hs1, W1d, b1d, hd1, NN);

    const int eb = (NE + 255) / 256;
    count_deg<<<eb, 256, 0, stream>>>(dst, deg);
    deg_blocksum<<<NB, 256, 0, stream>>>(deg, bsum);
    scan_bsum<<<1, 256, 0, stream>>>(bsum);
    write_rows<<<NB, 256, 0, stream>>>(deg, bsum, row_start);
    hipMemcpyAsync(cursor, row_start, (size_t)NN * 4, hipMemcpyDeviceToDevice, stream);
    scatter_src<<<eb, 256, 0, stream>>>(src, dst, cursor, src_sorted);

    gat1_fused<<<NN, 256, 0, stream>>>(hs1, hd1, attn1, src_sorted, row_start,
                                       W2s, b2s, W2d, b2d, hs2, hd2);

    node2_kernel<<<(NN + 3) / 4, 256, 0, stream>>>(hs2, hd2, attn2, src_sorted,
                                                   row_start, out);
}

// Round 8
// 329.809 us; speedup vs baseline: 1.3319x; 1.3319x over previous
//
#include <hip/hip_runtime.h>
#include <math.h>

#define NN 50000
#define NE 800000
#define NEG 0.2f
#define NB 196  // ceil(NN/256)

// ---------- fused dual GEMM: out[N,256] = feat[N,128] @ W + b  (gridDim.y picks W1s/W1d)
__global__ __launch_bounds__(256) void gemm_proj(
    const float* __restrict__ feat,
    const float* __restrict__ Wa, const float* __restrict__ ba, float* __restrict__ outa,
    const float* __restrict__ Wb, const float* __restrict__ bb, float* __restrict__ outb,
    int n_rows)
{
    const float* W = blockIdx.y ? Wb : Wa;
    const float* bv = blockIdx.y ? bb : ba;
    float* out = blockIdx.y ? outb : outa;

    __shared__ float fT[64][128];
    __shared__ float wT[16][256];

    const int row0 = blockIdx.x * 64;
    const int tid = threadIdx.x;

    {
        const float4* f4 = reinterpret_cast<const float4*>(feat);
#pragma unroll
        for (int p = 0; p < 8; ++p) {
            int idx = p * 256 + tid;
            int r = idx >> 5, c4 = idx & 31;
            int gr = row0 + r;
            float4 v = (gr < n_rows) ? f4[(size_t)gr * 32 + c4]
                                     : make_float4(0.f, 0.f, 0.f, 0.f);
            *reinterpret_cast<float4*>(&fT[r][c4 * 4]) = v;
        }
    }

    const int tm = tid >> 5;
    const int tn = tid & 31;
    float acc[8][8];
#pragma unroll
    for (int ri = 0; ri < 8; ++ri)
#pragma unroll
        for (int ci = 0; ci < 8; ++ci) acc[ri][ci] = 0.0f;

    const float4* W4 = reinterpret_cast<const float4*>(W);
    for (int k0 = 0; k0 < 128; k0 += 16) {
        __syncthreads();
#pragma unroll
        for (int p = 0; p < 4; ++p) {
            int idx = p * 256 + tid;
            int r = idx >> 6, c4 = idx & 63;
            *reinterpret_cast<float4*>(&wT[r][c4 * 4]) = W4[(size_t)(k0 + r) * 64 + c4];
        }
        __syncthreads();
#pragma unroll
        for (int kk = 0; kk < 16; ++kk) {
            float a[8], w[8];
#pragma unroll
            for (int ri = 0; ri < 8; ++ri) a[ri] = fT[tm + ri * 8][k0 + kk];
#pragma unroll
            for (int ci = 0; ci < 8; ++ci) w[ci] = wT[kk][tn + ci * 32];
#pragma unroll
            for (int ri = 0; ri < 8; ++ri)
#pragma unroll
                for (int ci = 0; ci < 8; ++ci)
                    acc[ri][ci] = fmaf(a[ri], w[ci], acc[ri][ci]);
        }
    }
#pragma unroll
    for (int ri = 0; ri < 8; ++ri) {
        int row = row0 + tm + ri * 8;
        if (row < n_rows) {
#pragma unroll
            for (int ci = 0; ci < 8; ++ci) {
                int col = tn + ci * 32;
                out[(size_t)row * 256 + col] = acc[ri][ci] + bv[col];
            }
        }
    }
}

// ---------------- CSR build ----------------
__global__ void count_deg(const int* __restrict__ dst, int* __restrict__ deg)
{
    int e = blockIdx.x * blockDim.x + threadIdx.x;
    if (e < NE) atomicAdd(&deg[dst[e]], 1);
}

__global__ __launch_bounds__(256) void deg_blocksum(const int* __restrict__ deg,
                                                    int* __restrict__ bsum)
{
    int i = blockIdx.x * 256 + threadIdx.x;
    int v = (i < NN) ? deg[i] : 0;
#pragma unroll
    for (int off = 32; off; off >>= 1) v += __shfl_xor(v, off);
    __shared__ int ws[4];
    if ((threadIdx.x & 63) == 0) ws[threadIdx.x >> 6] = v;
    __syncthreads();
    if (threadIdx.x == 0) bsum[blockIdx.x] = ws[0] + ws[1] + ws[2] + ws[3];
}

__global__ __launch_bounds__(256) void scan_bsum(int* __restrict__ bsum)
{
    __shared__ int tmp[256];
    int t = threadIdx.x;
    int orig = (t < NB) ? bsum[t] : 0;
    tmp[t] = orig;
    __syncthreads();
    for (int off = 1; off < 256; off <<= 1) {
        int v = (t >= off) ? tmp[t - off] : 0;
        __syncthreads();
        tmp[t] += v;
        __syncthreads();
    }
    if (t < NB) bsum[t] = tmp[t] - orig;  // exclusive prefix
}

__global__ __launch_bounds__(256) void write_rows(const int* __restrict__ deg,
                                                  const int* __restrict__ bpre,
                                                  int* __restrict__ row_start)
{
    int i = blockIdx.x * 256 + threadIdx.x;
    int d = (i < NN) ? deg[i] : 0;
    int lane = threadIdx.x & 63, w = threadIdx.x >> 6;
    int x = d;
#pragma unroll
    for (int off = 1; off < 64; off <<= 1) {
        int v = __shfl_up(x, off);
        if (lane >= off) x += v;
    }
    __shared__ int wsum[4];
    if (lane == 63) wsum[w] = x;
    __syncthreads();
    int woff = 0;
#pragma unroll
    for (int k = 0; k < 4; ++k)
        if (k < w) woff += wsum[k];
    if (i < NN) row_start[i] = bpre[blockIdx.x] + woff + x - d;
    if (blockIdx.x == 0 && threadIdx.x == 0) row_start[NN] = NE;
}

// cursor pre-initialized to row_start values (D2D copy) -> absolute positions
__global__ void scatter_src(const int* __restrict__ src, const int* __restrict__ dst,
                            int* __restrict__ cursor, int* __restrict__ src_sorted)
{
    int e = blockIdx.x * blockDim.x + threadIdx.x;
    if (e < NE) {
        int pos = atomicAdd(&cursor[dst[e]], 1);
        src_sorted[pos] = src[e];
    }
}

// ---- Layer-1 fused, single pass, defer-max, 2-edge software pipeline.
//      block=node, wave=edges (stride 4), lane=4 contiguous dims (coalesced 1KB row).
__global__ __launch_bounds__(256) void gat1_fused(
    const float* __restrict__ hs, const float* __restrict__ hd,
    const float* __restrict__ attn, const int* __restrict__ src_sorted,
    const int* __restrict__ row_start,
    const float* __restrict__ W2s, const float* __restrict__ b2s,
    const float* __restrict__ W2d, const float* __restrict__ b2d,
    float* __restrict__ hs2, float* __restrict__ hd2)
{
    __shared__ float mw[4][4];       // [wave][head] deferred max
    __shared__ float denw[4][4];     // [wave][head] denominator
    __shared__ float4 accs[4][64];   // [wave][lane] accumulators

    const int n = blockIdx.x;
    const int tid = threadIdx.x;
    const int w = tid >> 6;
    const int lane = tid & 63;
    const int q = lane & 15;
    const int hh = lane >> 4;        // head owning this lane's 4 dims
    const int beg = row_start[n], end_ = row_start[n + 1];

    const float4 a4 = *reinterpret_cast<const float4*>(&attn[lane * 4]);
    const float4 y4 = *reinterpret_cast<const float4*>(&hd[(size_t)n * 256 + lane * 4]);

    float m = -INFINITY, den = 0.0f;
    float4 acc = make_float4(0.f, 0.f, 0.f, 0.f);

    int i = beg + w;
    // -------- pipelined pairs: edges (i, i+4) with independent gathers --------
    for (; i + 4 < end_; i += 8) {
        const int sa = __builtin_amdgcn_readfirstlane(src_sorted[i]);
        const int sb = __builtin_amdgcn_readfirstlane(src_sorted[i + 4]);
        const float4 xa = *reinterpret_cast<const float4*>(&hs[(size_t)sa * 256 + lane * 4]);
        const float4 xb = *reinterpret_cast<const float4*>(&hs[(size_t)sb * 256 + lane * 4]);
        float ta, tb, pa, pb;
        ta = xa.x + y4.x; ta = fmaxf(ta, NEG * ta); pa = ta * a4.x;
        tb = xb.x + y4.x; tb = fmaxf(tb, NEG * tb); pb = tb * a4.x;
        ta = xa.y + y4.y; ta = fmaxf(ta, NEG * ta); pa = fmaf(ta, a4.y, pa);
        tb = xb.y + y4.y; tb = fmaxf(tb, NEG * tb); pb = fmaf(tb, a4.y, pb);
        ta = xa.z + y4.z; ta = fmaxf(ta, NEG * ta); pa = fmaf(ta, a4.z, pa);
        tb = xb.z + y4.z; tb = fmaxf(tb, NEG * tb); pb = fmaf(tb, a4.z, pb);
        ta = xa.w + y4.w; ta = fmaxf(ta, NEG * ta); pa = fmaf(ta, a4.w, pa);
        tb = xb.w + y4.w; tb = fmaxf(tb, NEG * tb); pb = fmaf(tb, a4.w, pb);
        pa += __shfl_xor(pa, 1);  pb += __shfl_xor(pb, 1);
        pa += __shfl_xor(pa, 2);  pb += __shfl_xor(pb, 2);
        pa += __shfl_xor(pa, 4);  pb += __shfl_xor(pb, 4);
        pa += __shfl_xor(pa, 8);  pb += __shfl_xor(pb, 8);
        // sequential state update (a then b); rescale is rare (defer-max T13)
        if (pa > m + 8.0f) {
            const float rs = __expf(m - pa);  // first edge: exp(-inf)=0
            den *= rs;
            acc.x *= rs; acc.y *= rs; acc.z *= rs; acc.w *= rs;
            m = pa;
        }
        const float wa = __expf(pa - m);
        den += wa;
        acc.x = fmaf(wa, xa.x, acc.x);
        acc.y = fmaf(wa, xa.y, acc.y);
        acc.z = fmaf(wa, xa.z, acc.z);
        acc.w = fmaf(wa, xa.w, acc.w);
        if (pb > m + 8.0f) {
            const float rs = __expf(m - pb);
            den *= rs;
            acc.x *= rs; acc.y *= rs; acc.z *= rs; acc.w *= rs;
            m = pb;
        }
        const float wb = __expf(pb - m);
        den += wb;
        acc.x = fmaf(wb, xb.x, acc.x);
        acc.y = fmaf(wb, xb.y, acc.y);
        acc.z = fmaf(wb, xb.z, acc.z);
        acc.w = fmaf(wb, xb.w, acc.w);
    }
    // -------- tail (at most one edge for this wave) --------
    if (i < end_) {
        const int s = __builtin_amdgcn_readfirstlane(src_sorted[i]);
        const float4 x = *reinterpret_cast<const float4*>(&hs[(size_t)s * 256 + lane * 4]);
        float t, p;
        t = x.x + y4.x; t = fmaxf(t, NEG * t); p  = t * a4.x;
        t = x.y + y4.y; t = fmaxf(t, NEG * t); p = fmaf(t, a4.y, p);
        t = x.z + y4.z; t = fmaxf(t, NEG * t); p = fmaf(t, a4.z, p);
        t = x.w + y4.w; t = fmaxf(t, NEG * t); p = fmaf(t, a4.w, p);
        p += __shfl_xor(p, 1);
        p += __shfl_xor(p, 2);
        p += __shfl_xor(p, 4);
        p += __shfl_xor(p, 8);
        if (p > m + 8.0f) {
            const float rs = __expf(m - p);
            den *= rs;
            acc.x *= rs; acc.y *= rs; acc.z *= rs; acc.w *= rs;
            m = p;
        }
        const float wv = __expf(p - m);
        den += wv;
        acc.x = fmaf(wv, x.x, acc.x);
        acc.y = fmaf(wv, x.y, acc.y);
        acc.z = fmaf(wv, x.z, acc.z);
        acc.w = fmaf(wv, x.w, acc.w);
    }

    if (q == 0) { mw[w][hh] = m; denw[w][hh] = den; }
    accs[w][lane] = acc;
    __syncthreads();

    if (w == 0) {
        // per-head global max across waves
        const float m0 = mw[0][hh], m1 = mw[1][hh], m2v = mw[2][hh], m3 = mw[3][hh];
        const float M = fmaxf(fmaxf(m0, m1), fmaxf(m2v, m3));
        float4 o = make_float4(0.f, 0.f, 0.f, 0.f);
        float dtot = 0.0f;
#pragma unroll
        for (int k = 0; k < 4; ++k) {
            const float mk = mw[k][hh];
            const float sc = (mk == -INFINITY) ? 0.0f : __expf(mk - M);
            dtot = fmaf(denw[k][hh], sc, dtot);
            const float4 av = accs[k][lane];
            o.x = fmaf(av.x, sc, o.x);
            o.y = fmaf(av.y, sc, o.y);
            o.z = fmaf(av.z, sc, o.z);
            o.w = fmaf(av.w, sc, o.w);
        }
        const float inv = (dtot > 0.0f) ? 1.0f / dtot : 0.0f;
        o.x *= inv; o.y *= inv; o.z *= inv; o.w *= inv;
        // ELU
        o.x = (o.x > 0.0f) ? o.x : __expf(o.x) - 1.0f;
        o.y = (o.y > 0.0f) ? o.y : __expf(o.y) - 1.0f;
        o.z = (o.z > 0.0f) ? o.z : __expf(o.z) - 1.0f;
        o.w = (o.w > 0.0f) ? o.w : __expf(o.w) - 1.0f;
        // fused layer-2 projection: rows 4*lane..4*lane+3 of W2 [256][2]
        const float4 wsa = *reinterpret_cast<const float4*>(&W2s[lane * 8]);
        const float4 wsb = *reinterpret_cast<const float4*>(&W2s[lane * 8 + 4]);
        const float4 wda = *reinterpret_cast<const float4*>(&W2d[lane * 8]);
        const float4 wdb = *reinterpret_cast<const float4*>(&W2d[lane * 8 + 4]);
        float ps0 = o.x * wsa.x + o.y * wsa.z + o.z * wsb.x + o.w * wsb.z;
        float ps1 = o.x * wsa.y + o.y * wsa.w + o.z * wsb.y + o.w * wsb.w;
        float pd0 = o.x * wda.x + o.y * wda.z + o.z * wdb.x + o.w * wdb.z;
        float pd1 = o.x * wda.y + o.y * wda.w + o.z * wdb.y + o.w * wdb.w;
#pragma unroll
        for (int off = 32; off; off >>= 1) {
            ps0 += __shfl_xor(ps0, off);
            ps1 += __shfl_xor(ps1, off);
            pd0 += __shfl_xor(pd0, off);
            pd1 += __shfl_xor(pd1, off);
        }
        if (lane == 0) {
            hs2[(size_t)n * 2 + 0] = ps0 + b2s[0];
            hs2[(size_t)n * 2 + 1] = ps1 + b2s[1];
            hd2[(size_t)n * 2 + 0] = pd0 + b2d[0];
            hd2[(size_t)n * 2 + 1] = pd1 + b2d[1];
        }
    }
}

// ---------------- Layer-2: 16 lanes per node (deg ~16), 16 nodes per block ----
__global__ __launch_bounds__(256) void node2_kernel(
    const float* __restrict__ hs2, const float* __restrict__ hd2,
    const float* __restrict__ attn2, const int* __restrict__ src_sorted,
    const int* __restrict__ row_start, float* __restrict__ out)
{
    const int n = blockIdx.x * 16 + (threadIdx.x >> 4);
    const int q = threadIdx.x & 15;
    if (n >= NN) return;
    const float a0 = attn2[0], a1 = attn2[1];
    const float h0 = hd2[n * 2 + 0], h1v = hd2[n * 2 + 1];
    const int beg = row_start[n], end_ = row_start[n + 1];
    float m = -INFINITY, den = 0.0f, A0 = 0.0f, A1 = 0.0f;
    for (int i = beg + q; i < end_; i += 16) {
        const int s = src_sorted[i];
        float x0 = hs2[s * 2 + 0], x1 = hs2[s * 2 + 1];
        float t0 = x0 + h0;  t0 = fmaxf(t0, NEG * t0);
        float t1 = x1 + h1v; t1 = fmaxf(t1, NEG * t1);
        float p = fmaf(t0, a0, t1 * a1);
        float mn = fmaxf(m, p);
        float c = __expf(m - mn);
        float w = __expf(p - mn);
        den = den * c + w;
        A0 = A0 * c + w * x0;
        A1 = A1 * c + w * x1;
        m = mn;
    }
#pragma unroll
    for (int off = 1; off < 16; off <<= 1) {
        float m2 = __shfl_xor(m, off, 16);
        float d2 = __shfl_xor(den, off, 16);
        float b0 = __shfl_xor(A0, off, 16);
        float b1 = __shfl_xor(A1, off, 16);
        float mn = fmaxf(m, m2);
        float c1 = (m < mn) ? __expf(m - mn) : 1.0f;
        float c2 = (m2 < mn) ? __expf(m2 - mn) : 1.0f;
        den = den * c1 + d2 * c2;
        A0 = A0 * c1 + b0 * c2;
        A1 = A1 * c1 + b1 * c2;
        m = mn;
    }
    if (q == 0) {
        out[n * 2 + 0] = (den > 0.0f) ? A0 / den : 0.0f;
        out[n * 2 + 1] = (den > 0.0f) ? A1 / den : 0.0f;
    }
}

// ---------------- launch ----------------
extern "C" void kernel_launch(void* const* d_in, const int* in_sizes, int n_in,
                              void* d_out, int out_size, void* d_ws, size_t ws_size,
                              hipStream_t stream)
{
    const float* feat  = (const float*)d_in[0];
    const int*   src   = (const int*)d_in[1];
    const int*   dst   = (const int*)d_in[2];
    const float* W1s   = (const float*)d_in[3];
    const float* b1s   = (const float*)d_in[4];
    const float* W1d   = (const float*)d_in[5];
    const float* b1d   = (const float*)d_in[6];
    const float* attn1 = (const float*)d_in[7];
    const float* W2s   = (const float*)d_in[8];
    const float* b2s   = (const float*)d_in[9];
    const float* W2d   = (const float*)d_in[10];
    const float* b2d   = (const float*)d_in[11];
    const float* attn2 = (const float*)d_in[12];
    float* out = (float*)d_out;

    char* ws = (char*)d_ws;
    size_t off = 0;
    auto alloc = [&](size_t bytes) {
        char* p = ws + off;
        off += (bytes + 255) & ~size_t(255);
        return p;
    };
    float* hs1        = (float*)alloc((size_t)NN * 256 * 4);
    float* hd1        = (float*)alloc((size_t)NN * 256 * 4);
    int*   src_sorted = (int*)alloc((size_t)NE * 4);
    int*   row_start  = (int*)alloc((size_t)(NN + 1) * 4);
    int*   deg        = (int*)alloc((size_t)NN * 4);
    int*   cursor     = (int*)alloc((size_t)NN * 4);
    int*   bsum       = (int*)alloc((size_t)NB * 4);
    float* hs2        = (float*)alloc((size_t)NN * 2 * 4);
    float* hd2        = (float*)alloc((size_t)NN * 2 * 4);
    (void)ws_size; (void)n_in; (void)in_sizes; (void)out_size;

    hipMemsetAsync(deg, 0, (size_t)NN * 4, stream);

    dim3 ggrid((NN + 63) / 64, 2);
    gemm_proj<<<ggrid, 256, 0, stream>>>(feat, W1s, b1s, hs1, W1d, b1d, hd1, NN);

    const int eb = (NE + 255) / 256;
    count_deg<<<eb, 256, 0, stream>>>(dst, deg);
    deg_blocksum<<<NB, 256, 0, stream>>>(deg, bsum);
    scan_bsum<<<1, 256, 0, stream>>>(bsum);
    write_rows<<<NB, 256, 0, stream>>>(deg, bsum, row_start);
    hipMemcpyAsync(cursor, row_start, (size_t)NN * 4, hipMemcpyDeviceToDevice, stream);
    scatter_src<<<eb, 256, 0, stream>>>(src, dst, cursor, src_sorted);

    gat1_fused<<<NN, 256, 0, stream>>>(hs1, hd1, attn1, src_sorted, row_start,
                                       W2s, b2s, W2d, b2d, hs2, hd2);

    node2_kernel<<<(NN + 15) / 16, 256, 0, stream>>>(hs2, hd2, attn2, src_sorted,
                                                     row_start, out);
}